// Round 1
// 297.340 us; speedup vs baseline: 1.0423x; 1.0423x over previous
//
#include <hip/hip_runtime.h>

#define BATCH 32
#define CDIM 512
#define NCL 27
#define HWDIM 3136            // 56*56
#define NPIX (BATCH * HWDIM)  // 100352
#define PXB 256               // pixels per block -> 1KB/channel contiguous
#define NBLK (NPIX / PXB)     // 392 blocks
#define NCHUNK 16             // 512 / 32 channels per K-chunk

typedef __attribute__((ext_vector_type(8))) short bf16x8;
typedef __attribute__((ext_vector_type(4))) float f32x4;

union I4B { int4 i; bf16x8 b; };

// ---------------------------------------------------------------------------
// Kernel 1: normalize codebook rows, emit MFMA B-fragments (hi/lo bf16
// split): wsB ushort index = ((chunk*4 + h*2 + part)*64 + lane)*8 + j,
// B[k][n]: n = (lane&15)+16h, k = chunk*32 + (lane>>4)*8 + j. n>=27 zero.
// 8 blocks: each recomputes norms (55KB codebook, L2-resident) and emits
// 2 chunks -> exactly one (chunk,h,lane) tuple per thread, 16B stores.
// Block 0 also zeroes out_loss for the fused atomic loss accumulation.
// ---------------------------------------------------------------------------
__global__ void prep_clusters_k(const float* __restrict__ cl,
                                unsigned short* __restrict__ wsB,
                                float* __restrict__ out_loss) {
    __shared__ float part[NCL][8];
    __shared__ float rnl[32];
    const int t = threadIdx.x;  // 256
    if (blockIdx.x == 0 && t == 0) out_loss[0] = 0.f;
    if (t < NCL * 8) {
        const int n = t >> 3, seg = t & 7;
        const float4* p = (const float4*)(cl + n * CDIM + seg * 64);
        float s = 0.f;
#pragma unroll
        for (int k = 0; k < 16; ++k) {
            const float4 v = p[k];
            s += v.x * v.x + v.y * v.y + v.z * v.z + v.w * v.w;
        }
        part[n][seg] = s;
    }
    __syncthreads();
    if (t < 32) {
        float r = 0.f;
        if (t < NCL) {
            float s = 0.f;
#pragma unroll
            for (int k = 0; k < 8; ++k) s += part[t][k];
            r = 1.f / fmaxf(sqrtf(s), 1e-12f);
        }
        rnl[t] = r;
    }
    __syncthreads();
    // one (chunk,h,lane) tuple per thread: 2 chunks * 2 h * 64 lanes = 256
    const int lane = t & 63;
    const int h = (t >> 6) & 1;
    const int chunk = 2 * blockIdx.x + (t >> 7);
    const int n = 16 * h + (lane & 15);
    const int c0 = chunk * 32 + ((lane >> 4) << 3);
    float w8[8];
    if (n < NCL) {
        const float4 a = *(const float4*)(cl + n * CDIM + c0);
        const float4 bq = *(const float4*)(cl + n * CDIM + c0 + 4);
        const float r = rnl[n];
        w8[0] = a.x * r;  w8[1] = a.y * r;  w8[2] = a.z * r;  w8[3] = a.w * r;
        w8[4] = bq.x * r; w8[5] = bq.y * r; w8[6] = bq.z * r; w8[7] = bq.w * r;
    } else {
#pragma unroll
        for (int j = 0; j < 8; ++j) w8[j] = 0.f;
    }
    int4 hi4, lo4;
#pragma unroll
    for (int d = 0; d < 4; ++d) {
        const unsigned int u0 = __float_as_uint(w8[2 * d]);
        const unsigned int u1 = __float_as_uint(w8[2 * d + 1]);
        ((unsigned int*)&hi4)[d] = (u0 >> 16) | (u1 & 0xffff0000u);
        const float h0 = __uint_as_float(u0 & 0xffff0000u);
        const float h1 = __uint_as_float(u1 & 0xffff0000u);
        const unsigned int l0 = __float_as_uint(w8[2 * d] - h0);      // exact
        const unsigned int l1 = __float_as_uint(w8[2 * d + 1] - h1);  // exact
        const unsigned int r0 = ((l0 + 0x7fffu + ((l0 >> 16) & 1u)) >> 16) & 0xffffu;
        const unsigned int r1 = ((l1 + 0x7fffu + ((l1 >> 16) & 1u)) >> 16) & 0xffffu;
        ((unsigned int*)&lo4)[d] = r0 | (r1 << 16);
    }
    unsigned short* base = wsB + ((size_t)(chunk * 4 + h * 2) * 64 + lane) * 8;
    *(int4*)base = hi4;
    *(int4*)(base + 512) = lo4;  // part stride = 64*8 ushorts
}

// ---------------------------------------------------------------------------
// Kernel 2: main. 392 blocks x 256 threads (4 waves). Wave w owns 64 px
// (block px w*64..w*64+63), all 512 channels, 32 padded clusters, as FOUR
// 16x16x32 MFMA tiles with row mapping px = 4*m + tile: lane m's float4
// x-load (px 4m..4m+3, channel q*8+j) provides component i directly as
// tile i's A element — no cross-lane moves. Per chunk: 8 dwordx4 x-loads
// (256 B contiguous per channel per wave, 1 KB per block), 4 dwordx4
// B-loads, hi/lo bf16 split, 24 MFMAs; 1-chunk-ahead prefetch.
// Loss is accumulated directly via one atomicAdd per block (out[0] zeroed
// by prep_clusters_k, which precedes this kernel in-stream).
// ---------------------------------------------------------------------------
__global__ __launch_bounds__(256, 2) void cluster_main_k(
    const float* __restrict__ x, const unsigned short* __restrict__ wsB,
    float* __restrict__ out_probs,  // = d_out + 1
    float* __restrict__ out_loss) {
    __shared__ float pr[NCL][PXB + 1];  // 27756 B, stride 257 (conflict-free)
    __shared__ float ss_sm[4][64];
    __shared__ float lossw[4];

    const int lane = threadIdx.x;  // 0..63
    const int w = threadIdx.y;     // wave 0..3
    const int m = lane & 15;
    const int q = lane >> 4;

    // lane's pixel quad (16-px groups never straddle a batch: 16 | 3136)
    const int p0 = blockIdx.x * PXB + w * 64 + 4 * m;
    const int b = p0 / HWDIM;
    const int hw0 = p0 - b * HWDIM;
    const float* xl = x + (size_t)b * CDIM * HWDIM + hw0;
    const int4* wsb4 = (const int4*)wsB;

    f32x4 acc[4][2];
#pragma unroll
    for (int i = 0; i < 4; ++i)
#pragma unroll
        for (int h = 0; h < 2; ++h)
            acc[i][h] = (f32x4){0.f, 0.f, 0.f, 0.f};
    float ssq[4] = {0.f, 0.f, 0.f, 0.f};

    float4 xv[8], xn[8];
    int4 bcur[4], bnxt[4];
#pragma unroll
    for (int j = 0; j < 8; ++j)
        xv[j] = *(const float4*)(xl + (size_t)(q * 8 + j) * HWDIM);
#pragma unroll
    for (int k = 0; k < 4; ++k) bcur[k] = wsb4[k * 64 + lane];

    for (int chunk = 0; chunk < NCHUNK; ++chunk) {
        if (chunk < NCHUNK - 1) {
            const float* xc = xl + (size_t)((chunk + 1) * 32 + q * 8) * HWDIM;
#pragma unroll
            for (int j = 0; j < 8; ++j)
                xn[j] = *(const float4*)(xc + (size_t)j * HWDIM);
#pragma unroll
            for (int k = 0; k < 4; ++k)
                bnxt[k] = wsb4[((chunk + 1) * 4 + k) * 64 + lane];
        }
#pragma unroll
        for (int j = 0; j < 8; ++j) {
            ssq[0] += xv[j].x * xv[j].x;
            ssq[1] += xv[j].y * xv[j].y;
            ssq[2] += xv[j].z * xv[j].z;
            ssq[3] += xv[j].w * xv[j].w;
        }
        I4B B0h, B0l, B1h, B1l;
        B0h.i = bcur[0]; B0l.i = bcur[1]; B1h.i = bcur[2]; B1l.i = bcur[3];
#pragma unroll
        for (int i = 0; i < 4; ++i) {
            I4B Ahi, Alo;
#pragma unroll
            for (int d = 0; d < 4; ++d) {
                const float x0 = ((const float*)&xv[2 * d])[i];
                const float x1 = ((const float*)&xv[2 * d + 1])[i];
                const unsigned int u0 = __float_as_uint(x0);
                const unsigned int u1 = __float_as_uint(x1);
                ((unsigned int*)&Ahi.i)[d] = (u0 >> 16) | (u1 & 0xffff0000u);
                const float h0 = __uint_as_float(u0 & 0xffff0000u);
                const float h1 = __uint_as_float(u1 & 0xffff0000u);
                const unsigned int l0 = __float_as_uint(x0 - h0);
                const unsigned int l1 = __float_as_uint(x1 - h1);
                ((unsigned int*)&Alo.i)[d] = (l0 >> 16) | (l1 & 0xffff0000u);
            }
            acc[i][0] = __builtin_amdgcn_mfma_f32_16x16x32_bf16(Ahi.b, B0h.b, acc[i][0], 0, 0, 0);
            acc[i][1] = __builtin_amdgcn_mfma_f32_16x16x32_bf16(Ahi.b, B1h.b, acc[i][1], 0, 0, 0);
            acc[i][0] = __builtin_amdgcn_mfma_f32_16x16x32_bf16(Ahi.b, B0l.b, acc[i][0], 0, 0, 0);
            acc[i][1] = __builtin_amdgcn_mfma_f32_16x16x32_bf16(Ahi.b, B1l.b, acc[i][1], 0, 0, 0);
            acc[i][0] = __builtin_amdgcn_mfma_f32_16x16x32_bf16(Alo.b, B0h.b, acc[i][0], 0, 0, 0);
            acc[i][1] = __builtin_amdgcn_mfma_f32_16x16x32_bf16(Alo.b, B1h.b, acc[i][1], 0, 0, 0);
        }
#pragma unroll
        for (int j = 0; j < 8; ++j) xv[j] = xn[j];
#pragma unroll
        for (int k = 0; k < 4; ++k) bcur[k] = bnxt[k];
    }

    // |x|^2: lane covers channels of its q only -> reduce across q-groups;
    // then lane m holds full ssq for px 4m+i (i=0..3)
#pragma unroll
    for (int i = 0; i < 4; ++i) {
        ssq[i] += __shfl_xor(ssq[i], 16, 64);
        ssq[i] += __shfl_xor(ssq[i], 32, 64);
    }
    if (lane < 16)
        *(float4*)&ss_sm[w][4 * lane] =
            (float4){ssq[0], ssq[1], ssq[2], ssq[3]};

    // softmax in C-layout: tile i, reg r -> px = 4*(q*4+r)+i, cols m & m+16
    const int col = m;
    const bool v1 = (col + 16) < NCL;
    float dot = 0.f;
#pragma unroll
    for (int i = 0; i < 4; ++i) {
#pragma unroll
        for (int r = 0; r < 4; ++r) {
            const int pxl = 4 * (q * 4 + r) + i;  // 0..63 within wave
            const float rn = 1.f / fmaxf(sqrtf(ss_sm[w][pxl]), 1e-12f);
            const float s0 = acc[i][0][r] * rn;
            const float s1 = acc[i][1][r] * rn;
            float mx = v1 ? fmaxf(s0, s1) : s0;
#pragma unroll
            for (int d = 1; d < 16; d <<= 1)
                mx = fmaxf(mx, __shfl_xor(mx, d, 64));
            const float e0 = __expf(2.f * (s0 - mx));
            const float e1 = v1 ? __expf(2.f * (s1 - mx)) : 0.f;
            float z = e0 + e1;
#pragma unroll
            for (int d = 1; d < 16; d <<= 1) z += __shfl_xor(z, d, 64);
            const float rz = 1.f / z;
            const float pp0 = e0 * rz;
            const float pp1 = e1 * rz;
            pr[col][w * 64 + pxl] = pp0;
            if (v1) pr[col + 16][w * 64 + pxl] = pp1;
            dot += pp0 * s0 + pp1 * s1;
        }
    }
#pragma unroll
    for (int d = 1; d < 64; d <<= 1) dot += __shfl_xor(dot, d, 64);
    if (lane == 0) lossw[w] = dot;
    __syncthreads();

    // coalesced prob stores: 27 rows x 256 contiguous floats
    const int t = w * 64 + lane;
    const int pflat = blockIdx.x * PXB + t;
    const int bb = pflat / HWDIM;
    const int hh = pflat - bb * HWDIM;
    float* ob = out_probs + (size_t)bb * NCL * HWDIM + hh;
#pragma unroll
    for (int n = 0; n < NCL; ++n) ob[(size_t)n * HWDIM] = pr[n][t];

    if (t == 0)
        atomicAdd(out_loss,
                  -(lossw[0] + lossw[1] + lossw[2] + lossw[3]) *
                      (1.f / (float)NPIX));
}

extern "C" void kernel_launch(void* const* d_in, const int* in_sizes, int n_in,
                              void* d_out, int out_size, void* d_ws,
                              size_t ws_size, hipStream_t stream) {
    const float* x = (const float*)d_in[0];        // [32,512,56,56]
    const float* clusters = (const float*)d_in[1]; // [27,512]
    float* out = (float*)d_out;                    // [loss | probs]
    unsigned short* wsB = (unsigned short*)d_ws;   // B frags: 32768 ushorts

    prep_clusters_k<<<8, 256, 0, stream>>>(clusters, wsB, out);
    cluster_main_k<<<NBLK, dim3(64, 4), 0, stream>>>(x, wsB, out + 1, out);
}

// Round 3
// 295.451 us; speedup vs baseline: 1.0489x; 1.0064x over previous
//
#include <hip/hip_runtime.h>

#define BATCH 32
#define CDIM 512
#define NCL 27
#define HWDIM 3136            // 56*56
#define NPIX (BATCH * HWDIM)  // 100352
#define PXB 256               // pixels per block -> 1KB/channel contiguous
#define NBLK (NPIX / PXB)     // 392 blocks
#define NCHUNK 16             // 512 / 32 channels per K-chunk

typedef __attribute__((ext_vector_type(8))) short bf16x8;
typedef __attribute__((ext_vector_type(4))) float f32x4;

union I4B { int4 i; bf16x8 b; };

// ---------------------------------------------------------------------------
// Kernel 1: zero the fused atomic loss accumulator (out[0]). Trivial; exists
// only because atomicAdd needs a zeroed base each iteration and cross-block
// ordering inside main cannot be guaranteed.
// ---------------------------------------------------------------------------
__global__ void zero_loss_k(float* __restrict__ out_loss) {
    if (threadIdx.x == 0) out_loss[0] = 0.f;
}

// ---------------------------------------------------------------------------
// Kernel 2 (fused): 392 blocks x 256 threads (4 waves). Wave w owns 64 px,
// all 512 channels, 32 padded clusters, as FOUR 16x16x32 MFMA tiles with row
// mapping px = 4*m + tile. Codebook prep is fused in: each block recomputes
// cluster norms (55KB codebook, L1/L2-hot; overlapped with the chunk-0 x
// prefetch issued first) and packs its B-fragments per chunk in-register
// from cl directly — bit-identical math to the old prep kernel, no wsB
// round-trip, no prep dispatch. Per chunk: 8 dwordx4 x-loads + 4 dwordx4
// cl-loads (L1-hot), hi/lo bf16 split for A and B, 24 MFMAs; 1-chunk-ahead
// prefetch. Loss via one atomicAdd per block (out[0] zeroed by kernel 1).
// ---------------------------------------------------------------------------
__global__ __launch_bounds__(256, 2) void cluster_main_k(
    const float* __restrict__ x, const float* __restrict__ cl,
    float* __restrict__ out_probs,  // = d_out + 1
    float* __restrict__ out_loss) {
    __shared__ float pr[NCL][PXB + 1];  // 27756 B, stride 257 (conflict-free)
    __shared__ float part[NCL][8];
    __shared__ float rnl[32];
    __shared__ float ss_sm[4][64];
    __shared__ float lossw[4];

    const int lane = threadIdx.x;  // 0..63
    const int w = threadIdx.y;     // wave 0..3
    const int m = lane & 15;
    const int q = lane >> 4;
    const int t = w * 64 + lane;

    // lane's pixel quad (16-px groups never straddle a batch: 16 | 3136)
    const int p0 = blockIdx.x * PXB + w * 64 + 4 * m;
    const int b = p0 / HWDIM;
    const int hw0 = p0 - b * HWDIM;
    const float* xl = x + (size_t)b * CDIM * HWDIM + hw0;

    // issue chunk-0 x loads FIRST: HBM latency hides under the norm phase
    float4 xv[8], xn[8];
#pragma unroll
    for (int j = 0; j < 8; ++j)
        xv[j] = *(const float4*)(xl + (size_t)(q * 8 + j) * HWDIM);

    // per-lane codebook rows for B fragments: n0 = m, n1 = 16+m (clamped)
    const int n1 = 16 + m;
    const float* r0p = cl + m * CDIM;
    const float* r1p = cl + (n1 < NCL ? n1 : 0) * CDIM;  // clamp: scaled by 0

    // chunk-0 codebook loads (normalization applied at pack time)
    float4 clc[4], cln[4];
    clc[0] = *(const float4*)(r0p + q * 8);
    clc[1] = *(const float4*)(r0p + q * 8 + 4);
    clc[2] = *(const float4*)(r1p + q * 8);
    clc[3] = *(const float4*)(r1p + q * 8 + 4);

    // ---- norm phase (bit-identical to old prep kernel) ----
    if (t < NCL * 8) {
        const int n = t >> 3, seg = t & 7;
        const float4* p = (const float4*)(cl + n * CDIM + seg * 64);
        float s = 0.f;
#pragma unroll
        for (int k = 0; k < 16; ++k) {
            const float4 v = p[k];
            s += v.x * v.x + v.y * v.y + v.z * v.z + v.w * v.w;
        }
        part[n][seg] = s;
    }
    __syncthreads();
    if (t < 32) {
        float r = 0.f;
        if (t < NCL) {
            float s = 0.f;
#pragma unroll
            for (int k = 0; k < 8; ++k) s += part[t][k];
            r = 1.f / fmaxf(sqrtf(s), 1e-12f);
        }
        rnl[t] = r;
    }
    __syncthreads();
    const float rn0 = rnl[m];
    const float rn1 = rnl[n1];  // 0 for n1 >= 27 (zeroes padded clusters)

    // pack one normalized 8-wide codebook slice into hi/lo bf16 fragments —
    // identical rounding math to the old prep kernel (probs bit-identical)
    auto packrow = [&](const float4& a, const float4& bq, float rn, int4& hi4,
                       int4& lo4) {
        float w8[8] = {a.x * rn,  a.y * rn,  a.z * rn,  a.w * rn,
                       bq.x * rn, bq.y * rn, bq.z * rn, bq.w * rn};
#pragma unroll
        for (int d = 0; d < 4; ++d) {
            const unsigned int u0 = __float_as_uint(w8[2 * d]);
            const unsigned int u1 = __float_as_uint(w8[2 * d + 1]);
            ((unsigned int*)&hi4)[d] = (u0 >> 16) | (u1 & 0xffff0000u);
            const float h0 = __uint_as_float(u0 & 0xffff0000u);
            const float h1 = __uint_as_float(u1 & 0xffff0000u);
            const unsigned int l0 = __float_as_uint(w8[2 * d] - h0);      // exact
            const unsigned int l1 = __float_as_uint(w8[2 * d + 1] - h1);  // exact
            const unsigned int r0 =
                ((l0 + 0x7fffu + ((l0 >> 16) & 1u)) >> 16) & 0xffffu;
            const unsigned int r1 =
                ((l1 + 0x7fffu + ((l1 >> 16) & 1u)) >> 16) & 0xffffu;
            ((unsigned int*)&lo4)[d] = r0 | (r1 << 16);
        }
    };

    f32x4 acc[4][2];
#pragma unroll
    for (int i = 0; i < 4; ++i)
#pragma unroll
        for (int h = 0; h < 2; ++h)
            acc[i][h] = (f32x4){0.f, 0.f, 0.f, 0.f};
    float ssq[4] = {0.f, 0.f, 0.f, 0.f};

    for (int chunk = 0; chunk < NCHUNK; ++chunk) {
        if (chunk < NCHUNK - 1) {
            const float* xc = xl + (size_t)((chunk + 1) * 32 + q * 8) * HWDIM;
#pragma unroll
            for (int j = 0; j < 8; ++j)
                xn[j] = *(const float4*)(xc + (size_t)j * HWDIM);
            const int cc = (chunk + 1) * 32 + q * 8;
            cln[0] = *(const float4*)(r0p + cc);
            cln[1] = *(const float4*)(r0p + cc + 4);
            cln[2] = *(const float4*)(r1p + cc);
            cln[3] = *(const float4*)(r1p + cc + 4);
        }
#pragma unroll
        for (int j = 0; j < 8; ++j) {
            ssq[0] += xv[j].x * xv[j].x;
            ssq[1] += xv[j].y * xv[j].y;
            ssq[2] += xv[j].z * xv[j].z;
            ssq[3] += xv[j].w * xv[j].w;
        }
        I4B B0h, B0l, B1h, B1l;
        packrow(clc[0], clc[1], rn0, B0h.i, B0l.i);
        packrow(clc[2], clc[3], rn1, B1h.i, B1l.i);
#pragma unroll
        for (int i = 0; i < 4; ++i) {
            I4B Ahi, Alo;
#pragma unroll
            for (int d = 0; d < 4; ++d) {
                const float x0 = ((const float*)&xv[2 * d])[i];
                const float x1 = ((const float*)&xv[2 * d + 1])[i];
                const unsigned int u0 = __float_as_uint(x0);
                const unsigned int u1 = __float_as_uint(x1);
                ((unsigned int*)&Ahi.i)[d] = (u0 >> 16) | (u1 & 0xffff0000u);
                const float h0 = __uint_as_float(u0 & 0xffff0000u);
                const float h1 = __uint_as_float(u1 & 0xffff0000u);
                const unsigned int l0 = __float_as_uint(x0 - h0);
                const unsigned int l1 = __float_as_uint(x1 - h1);
                ((unsigned int*)&Alo.i)[d] = (l0 >> 16) | (l1 & 0xffff0000u);
            }
            acc[i][0] = __builtin_amdgcn_mfma_f32_16x16x32_bf16(Ahi.b, B0h.b, acc[i][0], 0, 0, 0);
            acc[i][1] = __builtin_amdgcn_mfma_f32_16x16x32_bf16(Ahi.b, B1h.b, acc[i][1], 0, 0, 0);
            acc[i][0] = __builtin_amdgcn_mfma_f32_16x16x32_bf16(Ahi.b, B0l.b, acc[i][0], 0, 0, 0);
            acc[i][1] = __builtin_amdgcn_mfma_f32_16x16x32_bf16(Ahi.b, B1l.b, acc[i][1], 0, 0, 0);
            acc[i][0] = __builtin_amdgcn_mfma_f32_16x16x32_bf16(Alo.b, B0h.b, acc[i][0], 0, 0, 0);
            acc[i][1] = __builtin_amdgcn_mfma_f32_16x16x32_bf16(Alo.b, B1h.b, acc[i][1], 0, 0, 0);
        }
#pragma unroll
        for (int j = 0; j < 8; ++j) xv[j] = xn[j];
#pragma unroll
        for (int k = 0; k < 4; ++k) clc[k] = cln[k];
    }

    // |x|^2: lane covers channels of its q only -> reduce across q-groups;
    // then lane m holds full ssq for px 4m+i (i=0..3)
#pragma unroll
    for (int i = 0; i < 4; ++i) {
        ssq[i] += __shfl_xor(ssq[i], 16, 64);
        ssq[i] += __shfl_xor(ssq[i], 32, 64);
    }
    if (lane < 16)
        *(float4*)&ss_sm[w][4 * lane] =
            (float4){ssq[0], ssq[1], ssq[2], ssq[3]};

    // softmax in C-layout: tile i, reg r -> px = 4*(q*4+r)+i, cols m & m+16
    const int col = m;
    const bool v1 = (col + 16) < NCL;
    float dot = 0.f;
#pragma unroll
    for (int i = 0; i < 4; ++i) {
#pragma unroll
        for (int r = 0; r < 4; ++r) {
            const int pxl = 4 * (q * 4 + r) + i;  // 0..63 within wave
            const float rn = 1.f / fmaxf(sqrtf(ss_sm[w][pxl]), 1e-12f);
            const float s0 = acc[i][0][r] * rn;
            const float s1 = acc[i][1][r] * rn;
            float mx = v1 ? fmaxf(s0, s1) : s0;
#pragma unroll
            for (int d = 1; d < 16; d <<= 1)
                mx = fmaxf(mx, __shfl_xor(mx, d, 64));
            const float e0 = __expf(2.f * (s0 - mx));
            const float e1 = v1 ? __expf(2.f * (s1 - mx)) : 0.f;
            float z = e0 + e1;
#pragma unroll
            for (int d = 1; d < 16; d <<= 1) z += __shfl_xor(z, d, 64);
            const float rz = 1.f / z;
            const float pp0 = e0 * rz;
            const float pp1 = e1 * rz;
            pr[col][w * 64 + pxl] = pp0;
            if (v1) pr[col + 16][w * 64 + pxl] = pp1;
            dot += pp0 * s0 + pp1 * s1;
        }
    }
#pragma unroll
    for (int d = 1; d < 64; d <<= 1) dot += __shfl_xor(dot, d, 64);
    if (lane == 0) lossw[w] = dot;
    __syncthreads();

    // coalesced prob stores: 27 rows x 256 contiguous floats
    const int pflat = blockIdx.x * PXB + t;
    const int bb = pflat / HWDIM;
    const int hh = pflat - bb * HWDIM;
    float* ob = out_probs + (size_t)bb * NCL * HWDIM + hh;
#pragma unroll
    for (int n = 0; n < NCL; ++n) ob[(size_t)n * HWDIM] = pr[n][t];

    if (t == 0)
        atomicAdd(out_loss,
                  -(lossw[0] + lossw[1] + lossw[2] + lossw[3]) *
                      (1.f / (float)NPIX));
}

extern "C" void kernel_launch(void* const* d_in, const int* in_sizes, int n_in,
                              void* d_out, int out_size, void* d_ws,
                              size_t ws_size, hipStream_t stream) {
    const float* x = (const float*)d_in[0];        // [32,512,56,56]
    const float* clusters = (const float*)d_in[1]; // [27,512]
    float* out = (float*)d_out;                    // [loss | probs]

    zero_loss_k<<<1, 64, 0, stream>>>(out);
    cluster_main_k<<<NBLK, dim3(64, 4), 0, stream>>>(x, clusters, out + 1, out);
}